// Round 1
// baseline (631.493 us; speedup 1.0000x reference)
//
#include <hip/hip_runtime.h>

#define FD 128  // feature dim, fixed by problem

// ---------------- CSR construction ----------------

__global__ __launch_bounds__(256) void k_count(const int* __restrict__ dst,
                                               int* __restrict__ deg, int E) {
  int e = blockIdx.x * 256 + threadIdx.x;
  if (e < E) atomicAdd(&deg[dst[e]], 1);
}

__global__ __launch_bounds__(256) void k_dis(const int* __restrict__ deg,
                                             float* __restrict__ dis, int N) {
  int i = blockIdx.x * 256 + threadIdx.x;
  if (i < N) dis[i] = rsqrtf((float)(deg[i] + 1));  // +1 self-loop
}

// pass A: per-256-block exclusive scan + block totals
__global__ __launch_bounds__(256) void k_scanA(const int* __restrict__ deg,
                                               int* __restrict__ offtmp,
                                               int* __restrict__ bsum, int N) {
  __shared__ int s[256];
  int i = blockIdx.x * 256 + threadIdx.x;
  int v = (i < N) ? deg[i] : 0;
  s[threadIdx.x] = v;
  __syncthreads();
#pragma unroll
  for (int ofs = 1; ofs < 256; ofs <<= 1) {
    int t = (threadIdx.x >= ofs) ? s[threadIdx.x - ofs] : 0;
    __syncthreads();
    s[threadIdx.x] += t;
    __syncthreads();
  }
  if (i < N) offtmp[i] = s[threadIdx.x] - v;  // exclusive
  if (threadIdx.x == 255) bsum[blockIdx.x] = s[255];
}

// pass B: serial scan of ~391 block sums (trivial)
__global__ void k_scanB(int* __restrict__ bsum, int nb) {
  if (threadIdx.x == 0) {
    int run = 0;
    for (int i = 0; i < nb; ++i) { int v = bsum[i]; bsum[i] = run; run += v; }
  }
}

__global__ __launch_bounds__(256) void k_scanC(const int* __restrict__ offtmp,
                                               const int* __restrict__ bsum,
                                               int* __restrict__ off, int N, int E) {
  int i = blockIdx.x * 256 + threadIdx.x;
  if (i < N) off[i] = offtmp[i] + bsum[i >> 8];
  if (i == 0) off[N] = E;
}

__global__ __launch_bounds__(256) void k_fill(const int* __restrict__ src,
                                              const int* __restrict__ dst,
                                              const float* __restrict__ dis,
                                              const int* __restrict__ off,
                                              int* __restrict__ cursor,
                                              int* __restrict__ csr_src,
                                              float* __restrict__ csr_w, int E) {
  int e = blockIdx.x * 256 + threadIdx.x;
  if (e >= E) return;
  int d = dst[e], s = src[e];
  int pos = off[d] + atomicAdd(&cursor[d], 1);
  csr_src[pos] = s;
  csr_w[pos] = dis[s] * dis[d];
}

// ---------------- GEMM: H = A @ W  (A: N x 128, W: 128 x 128) ----------------
// W fully resident in LDS (64 KB). 128-row tile per block; 8x8 micro-tile per
// thread; k unrolled by 4 with float4 A loads (16 lanes broadcast same addr -> L1).
__global__ __launch_bounds__(256) void k_gemm(const float* __restrict__ A,
                                              const float* __restrict__ Wg,
                                              float* __restrict__ H, int N) {
  __shared__ float ws[FD * FD];  // 64 KB exactly
  int tid = threadIdx.x;
  int row0 = blockIdx.x * FD;
#pragma unroll
  for (int it = 0; it < 16; ++it) {
    int idx = it * 1024 + tid * 4;
    *(float4*)&ws[idx] = *(const float4*)&Wg[idx];
  }
  __syncthreads();

  int cg = (tid & 15) * 8;   // 8 cols per thread
  int rg = (tid >> 4) * 8;   // 8 rows per thread
  const float* Arow[8];
#pragma unroll
  for (int i = 0; i < 8; ++i) {
    int gr = row0 + rg + i;
    Arow[i] = A + (size_t)((gr < N) ? gr : 0) * FD;  // clamp: dummy in-bounds read
  }
  float acc[8][8];
#pragma unroll
  for (int i = 0; i < 8; ++i)
#pragma unroll
    for (int j = 0; j < 8; ++j) acc[i][j] = 0.f;

  for (int k = 0; k < FD; k += 4) {
    float4 wv[4][2];
#pragma unroll
    for (int j = 0; j < 4; ++j) {
      wv[j][0] = *(const float4*)&ws[(k + j) * FD + cg];
      wv[j][1] = *(const float4*)&ws[(k + j) * FD + cg + 4];
    }
#pragma unroll
    for (int i = 0; i < 8; ++i) {
      float4 a = *(const float4*)(Arow[i] + k);
      float av[4] = {a.x, a.y, a.z, a.w};
#pragma unroll
      for (int j = 0; j < 4; ++j) {
        const float* wj = (const float*)&wv[j][0];
#pragma unroll
        for (int cc = 0; cc < 8; ++cc)
          acc[i][cc] = fmaf(av[j], wj[cc], acc[i][cc]);
      }
    }
  }

#pragma unroll
  for (int i = 0; i < 8; ++i) {
    int gr = row0 + rg + i;
    if (gr < N) {
      float4 o0 = make_float4(acc[i][0], acc[i][1], acc[i][2], acc[i][3]);
      float4 o1 = make_float4(acc[i][4], acc[i][5], acc[i][6], acc[i][7]);
      *(float4*)&H[(size_t)gr * FD + cg] = o0;
      *(float4*)&H[(size_t)gr * FD + cg + 4] = o1;
    }
  }
}

// ---------------- Aggregation: out = relu(A_norm @ h + b) ----------------
// One wave per node; lane holds float2 (64 lanes x 8 B = 512 B row, coalesced).
__global__ __launch_bounds__(256) void k_agg(const float* __restrict__ h,
                                             const int* __restrict__ off,
                                             const int* __restrict__ csr_src,
                                             const float* __restrict__ csr_w,
                                             const float* __restrict__ dis,
                                             const float* __restrict__ bias,
                                             float* __restrict__ out, int N) {
  int wid = threadIdx.x >> 6;
  int lane = threadIdx.x & 63;
  int i = blockIdx.x * 4 + wid;
  if (i >= N) return;
  const float2* h2 = (const float2*)h;
  float di = dis[i];
  float wself = di * di;
  float2 hv = h2[(size_t)i * 64 + lane];
  float ax = wself * hv.x, ay = wself * hv.y;
  float bx = 0.f, by = 0.f;  // second accumulator for 2-way MLP
  int p = off[i], p1 = off[i + 1];
  for (; p + 1 < p1; p += 2) {
    int s0 = csr_src[p], s1 = csr_src[p + 1];
    float w0 = csr_w[p], w1 = csr_w[p + 1];
    float2 v0 = h2[(size_t)s0 * 64 + lane];
    float2 v1 = h2[(size_t)s1 * 64 + lane];
    ax = fmaf(w0, v0.x, ax); ay = fmaf(w0, v0.y, ay);
    bx = fmaf(w1, v1.x, bx); by = fmaf(w1, v1.y, by);
  }
  if (p < p1) {
    int s0 = csr_src[p];
    float w0 = csr_w[p];
    float2 v0 = h2[(size_t)s0 * 64 + lane];
    ax = fmaf(w0, v0.x, ax); ay = fmaf(w0, v0.y, ay);
  }
  float2 bb = ((const float2*)bias)[lane];
  float2 o;
  o.x = fmaxf(ax + bx + bb.x, 0.f);
  o.y = fmaxf(ay + by + bb.y, 0.f);
  ((float2*)out)[(size_t)i * 64 + lane] = o;
}

// ---------------- launch ----------------

extern "C" void kernel_launch(void* const* d_in, const int* in_sizes, int n_in,
                              void* d_out, int out_size, void* d_ws, size_t ws_size,
                              hipStream_t stream) {
  const float* x = (const float*)d_in[0];
  const int* ei = (const int*)d_in[1];
  const float* Wg = (const float*)d_in[2];
  const float* b = (const float*)d_in[3];
  int N = in_sizes[0] / FD;
  int E = in_sizes[1] / 2;
  const int* src = ei;       // edge_index[0]
  const int* dst = ei + E;   // edge_index[1]

  char* p = (char*)d_ws;
  auto alloc = [&](size_t bytes) {
    void* r = (void*)p;
    p += (bytes + 255) & ~(size_t)255;
    return r;
  };
  int* deg = (int*)alloc((size_t)N * 4);
  int* cursor = (int*)alloc((size_t)N * 4);
  float* dis = (float*)alloc((size_t)N * 4);
  int* offtmp = (int*)alloc((size_t)N * 4);
  int nb = (N + 255) / 256;
  int* bsum = (int*)alloc((size_t)nb * 4);
  int* off = (int*)alloc((size_t)(N + 1) * 4);
  int* csr_src = (int*)alloc((size_t)E * 4);
  float* csr_w = (float*)alloc((size_t)E * 4);
  float* h = (float*)alloc((size_t)N * FD * 4);
  float* xo = (float*)d_out;  // d_out doubles as the x ping buffer

  hipMemsetAsync(deg, 0, (size_t)N * 4, stream);
  hipMemsetAsync(cursor, 0, (size_t)N * 4, stream);

  int gE = (E + 255) / 256, gN = (N + 255) / 256;
  k_count<<<gE, 256, 0, stream>>>(dst, deg, E);
  k_dis<<<gN, 256, 0, stream>>>(deg, dis, N);
  k_scanA<<<nb, 256, 0, stream>>>(deg, offtmp, bsum, N);
  k_scanB<<<1, 64, 0, stream>>>(bsum, nb);
  k_scanC<<<gN, 256, 0, stream>>>(offtmp, bsum, off, N, E);
  k_fill<<<gE, 256, 0, stream>>>(src, dst, dis, off, cursor, csr_src, csr_w, E);

  int gG = (N + FD - 1) / FD;
  int gA = (N + 3) / 4;
  const float* xin = x;
  for (int l = 0; l < 3; ++l) {
    k_gemm<<<gG, 256, 0, stream>>>(xin, Wg, h, N);
    k_agg<<<gA, 256, 0, stream>>>(h, off, csr_src, csr_w, dis, b, xo, N);
    xin = xo;
  }
}

// Round 2
// 453.105 us; speedup vs baseline: 1.3937x; 1.3937x over previous
//
#include <hip/hip_runtime.h>

#define FD 128  // feature dim, fixed by problem

typedef __attribute__((ext_vector_type(8))) short short8;   // 8 bf16 in 4 VGPRs
typedef __attribute__((ext_vector_type(4))) float floatx4;  // MFMA acc

__device__ inline unsigned short f2bf(float f) {  // fp32 -> bf16 bits, RNE
  unsigned u = __float_as_uint(f);
  u += 0x7fffu + ((u >> 16) & 1u);
  return (unsigned short)(u >> 16);
}
__device__ inline float bf2f(unsigned short s) {
  return __uint_as_float(((unsigned)s) << 16);
}

// ---------------- CSR construction ----------------

__global__ __launch_bounds__(256) void k_count(const int* __restrict__ dst,
                                               int* __restrict__ deg, int E) {
  int e = blockIdx.x * 256 + threadIdx.x;
  if (e < E) atomicAdd(&deg[dst[e]], 1);
}

__global__ __launch_bounds__(256) void k_dis(const int* __restrict__ deg,
                                             float* __restrict__ dis, int N) {
  int i = blockIdx.x * 256 + threadIdx.x;
  if (i < N) dis[i] = rsqrtf((float)(deg[i] + 1));  // +1 self-loop
}

__global__ __launch_bounds__(256) void k_scanA(const int* __restrict__ deg,
                                               int* __restrict__ offtmp,
                                               int* __restrict__ bsum, int N) {
  __shared__ int s[256];
  int i = blockIdx.x * 256 + threadIdx.x;
  int v = (i < N) ? deg[i] : 0;
  s[threadIdx.x] = v;
  __syncthreads();
#pragma unroll
  for (int ofs = 1; ofs < 256; ofs <<= 1) {
    int t = (threadIdx.x >= ofs) ? s[threadIdx.x - ofs] : 0;
    __syncthreads();
    s[threadIdx.x] += t;
    __syncthreads();
  }
  if (i < N) offtmp[i] = s[threadIdx.x] - v;  // exclusive
  if (threadIdx.x == 255) bsum[blockIdx.x] = s[255];
}

__global__ void k_scanB(int* __restrict__ bsum, int nb) {
  if (threadIdx.x == 0) {
    int run = 0;
    for (int i = 0; i < nb; ++i) { int v = bsum[i]; bsum[i] = run; run += v; }
  }
}

__global__ __launch_bounds__(256) void k_scanC(const int* __restrict__ offtmp,
                                               const int* __restrict__ bsum,
                                               int* __restrict__ off, int N, int E) {
  int i = blockIdx.x * 256 + threadIdx.x;
  if (i < N) off[i] = offtmp[i] + bsum[i >> 8];
  if (i == 0) off[N] = E;
}

// packed edge record: .x = src, .y = bits(dis[src]*dis[dst])
__global__ __launch_bounds__(256) void k_fill(const int* __restrict__ src,
                                              const int* __restrict__ dst,
                                              const float* __restrict__ dis,
                                              const int* __restrict__ off,
                                              int* __restrict__ cursor,
                                              int2* __restrict__ ew, int E) {
  int e = blockIdx.x * 256 + threadIdx.x;
  if (e >= E) return;
  int d = dst[e], s = src[e];
  int pos = off[d] + atomicAdd(&cursor[d], 1);
  ew[pos] = make_int2(s, __float_as_int(dis[s] * dis[d]));
}

// ---------------- W pre-swizzle: fp32 W -> hi/lo bf16 in MFMA B-frag order ----
// Wf[ct][kt][lane][j]: k = kt*32 + (lane>>4)*8 + j, n = ct*16 + (lane&15)
__global__ __launch_bounds__(256) void k_wsplit(const float* __restrict__ W,
                                                short* __restrict__ hi,
                                                short* __restrict__ lo) {
  int idx = blockIdx.x * 256 + threadIdx.x;  // 0..16383
  int j = idx & 7, lane = (idx >> 3) & 63, kt = (idx >> 9) & 3, ct = idx >> 11;
  int k = kt * 32 + (lane >> 4) * 8 + j;
  int n = ct * 16 + (lane & 15);
  float w = W[k * FD + n];
  unsigned short h = f2bf(w);
  hi[idx] = (short)h;
  lo[idx] = (short)f2bf(w - bf2f(h));
}

// ---------------- GEMM: H(bf16) = A(fp32) @ W via bf16x2 MFMA ----------------
// 4 waves/block, 16 rows/wave. A split hi/lo in-register; 3 mfma per k-tile:
// Ahi*Whi + Alo*Whi + Ahi*Wlo (lo*lo dropped, ~2^-18 rel).
__global__ __launch_bounds__(256) void k_gemm(const float* __restrict__ A,
                                              const short* __restrict__ Wf_hi,
                                              const short* __restrict__ Wf_lo,
                                              unsigned short* __restrict__ H, int N) {
  int tid = threadIdx.x;
  int wid = tid >> 6, lane = tid & 63;
  int quad = lane >> 4, m = lane & 15;
  int r0 = blockIdx.x * 64 + wid * 16;
  int arow = r0 + m;
  if (arow >= N) arow = N - 1;  // clamp; OOB rows never stored
  const float* ap = A + (size_t)arow * FD;

  short8 ahi[4], alo[4];
#pragma unroll
  for (int kt = 0; kt < 4; ++kt) {
    const float* p = ap + kt * 32 + quad * 8;
    float4 a0 = *(const float4*)p;
    float4 a1 = *(const float4*)(p + 4);
    float av[8] = {a0.x, a0.y, a0.z, a0.w, a1.x, a1.y, a1.z, a1.w};
#pragma unroll
    for (int j = 0; j < 8; ++j) {
      unsigned short hb = f2bf(av[j]);
      ahi[kt][j] = (short)hb;
      alo[kt][j] = (short)f2bf(av[j] - bf2f(hb));
    }
  }

#pragma unroll
  for (int ct = 0; ct < 8; ++ct) {
    floatx4 acc = {0.f, 0.f, 0.f, 0.f};
#pragma unroll
    for (int kt = 0; kt < 4; ++kt) {
      size_t fo = (size_t)(((ct << 2) + kt) * 64 + lane) * 8;
      short8 bhi = *(const short8*)&Wf_hi[fo];
      short8 blo = *(const short8*)&Wf_lo[fo];
      acc = __builtin_amdgcn_mfma_f32_16x16x32_bf16(ahi[kt], bhi, acc, 0, 0, 0);
      acc = __builtin_amdgcn_mfma_f32_16x16x32_bf16(alo[kt], bhi, acc, 0, 0, 0);
      acc = __builtin_amdgcn_mfma_f32_16x16x32_bf16(ahi[kt], blo, acc, 0, 0, 0);
    }
    // C/D: row = quad*4 + reg, col = lane&15
#pragma unroll
    for (int r = 0; r < 4; ++r) {
      int row = r0 + quad * 4 + r;
      if (row < N) H[(size_t)row * FD + ct * 16 + m] = f2bf(acc[r]);
    }
  }
}

// ---------------- Aggregation: out = relu(A_norm @ h + b), h is bf16 --------
// One wave per node; lane holds 1 dword = 2 bf16 features. 4-way edge unroll.
__global__ __launch_bounds__(256) void k_agg(const unsigned int* __restrict__ h,
                                             const int* __restrict__ off,
                                             const int2* __restrict__ ew,
                                             const float* __restrict__ dis,
                                             const float* __restrict__ bias,
                                             float* __restrict__ out, int N) {
  int wid = threadIdx.x >> 6;
  int lane = threadIdx.x & 63;
  int i = blockIdx.x * 4 + wid;
  if (i >= N) return;
  float di = dis[i];
  float wself = di * di;
  unsigned v = h[(size_t)i * 64 + lane];
  float a0 = wself * __uint_as_float(v << 16);
  float a1 = wself * __uint_as_float(v & 0xffff0000u);
  float b0 = 0.f, b1 = 0.f, c0 = 0.f, c1 = 0.f, d0 = 0.f, d1 = 0.f;
  int p = off[i], p1 = off[i + 1];
  for (; p + 3 < p1; p += 4) {
    int2 e0 = ew[p], e1 = ew[p + 1], e2 = ew[p + 2], e3 = ew[p + 3];
    unsigned v0 = h[(size_t)e0.x * 64 + lane];
    unsigned v1 = h[(size_t)e1.x * 64 + lane];
    unsigned v2 = h[(size_t)e2.x * 64 + lane];
    unsigned v3 = h[(size_t)e3.x * 64 + lane];
    float w0 = __int_as_float(e0.y), w1 = __int_as_float(e1.y);
    float w2 = __int_as_float(e2.y), w3 = __int_as_float(e3.y);
    a0 = fmaf(w0, __uint_as_float(v0 << 16), a0);
    a1 = fmaf(w0, __uint_as_float(v0 & 0xffff0000u), a1);
    b0 = fmaf(w1, __uint_as_float(v1 << 16), b0);
    b1 = fmaf(w1, __uint_as_float(v1 & 0xffff0000u), b1);
    c0 = fmaf(w2, __uint_as_float(v2 << 16), c0);
    c1 = fmaf(w2, __uint_as_float(v2 & 0xffff0000u), c1);
    d0 = fmaf(w3, __uint_as_float(v3 << 16), d0);
    d1 = fmaf(w3, __uint_as_float(v3 & 0xffff0000u), d1);
  }
  for (; p < p1; ++p) {
    int2 e0 = ew[p];
    unsigned v0 = h[(size_t)e0.x * 64 + lane];
    float w0 = __int_as_float(e0.y);
    a0 = fmaf(w0, __uint_as_float(v0 << 16), a0);
    a1 = fmaf(w0, __uint_as_float(v0 & 0xffff0000u), a1);
  }
  float2 bb = ((const float2*)bias)[lane];
  float o0 = fmaxf(a0 + b0 + c0 + d0 + bb.x, 0.f);
  float o1 = fmaxf(a1 + b1 + c1 + d1 + bb.y, 0.f);
  ((float2*)out)[(size_t)i * 64 + lane] = make_float2(o0, o1);
}

// ---------------- launch ----------------

extern "C" void kernel_launch(void* const* d_in, const int* in_sizes, int n_in,
                              void* d_out, int out_size, void* d_ws, size_t ws_size,
                              hipStream_t stream) {
  const float* x = (const float*)d_in[0];
  const int* ei = (const int*)d_in[1];
  const float* Wg = (const float*)d_in[2];
  const float* b = (const float*)d_in[3];
  int N = in_sizes[0] / FD;
  int E = in_sizes[1] / 2;
  const int* src = ei;      // edge_index[0]
  const int* dst = ei + E;  // edge_index[1]

  char* p = (char*)d_ws;
  auto alloc = [&](size_t bytes) {
    void* r = (void*)p;
    p += (bytes + 255) & ~(size_t)255;
    return r;
  };
  int* deg = (int*)alloc((size_t)N * 4);
  int* cursor = (int*)alloc((size_t)N * 4);
  float* dis = (float*)alloc((size_t)N * 4);
  int* offtmp = (int*)alloc((size_t)N * 4);
  int nb = (N + 255) / 256;
  int* bsum = (int*)alloc((size_t)nb * 4);
  int* off = (int*)alloc((size_t)(N + 1) * 4);
  int2* ew = (int2*)alloc((size_t)E * 8);
  unsigned short* h = (unsigned short*)alloc((size_t)N * FD * 2);  // bf16 H
  short* wf_hi = (short*)alloc((size_t)FD * FD * 2);
  short* wf_lo = (short*)alloc((size_t)FD * FD * 2);
  float* xo = (float*)d_out;  // d_out doubles as the x ping buffer

  hipMemsetAsync(deg, 0, (size_t)N * 4, stream);
  hipMemsetAsync(cursor, 0, (size_t)N * 4, stream);

  int gE = (E + 255) / 256, gN = (N + 255) / 256;
  k_count<<<gE, 256, 0, stream>>>(dst, deg, E);
  k_dis<<<gN, 256, 0, stream>>>(deg, dis, N);
  k_scanA<<<nb, 256, 0, stream>>>(deg, offtmp, bsum, N);
  k_scanB<<<1, 64, 0, stream>>>(bsum, nb);
  k_scanC<<<gN, 256, 0, stream>>>(offtmp, bsum, off, N, E);
  k_fill<<<gE, 256, 0, stream>>>(src, dst, dis, off, cursor, ew, E);
  k_wsplit<<<FD * FD / 256, 256, 0, stream>>>(Wg, wf_hi, wf_lo);

  int gG = (N + 63) / 64;
  int gA = (N + 3) / 4;
  const float* xin = x;
  for (int l = 0; l < 3; ++l) {
    k_gemm<<<gG, 256, 0, stream>>>(xin, wf_hi, wf_lo, h, N);
    k_agg<<<gA, 256, 0, stream>>>((const unsigned int*)h, off, ew, dis, b, xo, N);
    xin = xo;
  }
}

// Round 3
// 361.390 us; speedup vs baseline: 1.7474x; 1.2538x over previous
//
#include <hip/hip_runtime.h>

#define FD 128  // feature dim, fixed by problem

typedef __attribute__((ext_vector_type(8))) short short8;   // 8 bf16 in 4 VGPRs
typedef __attribute__((ext_vector_type(4))) float floatx4;  // MFMA acc

__device__ inline unsigned short f2bf(float f) {  // fp32 -> bf16 bits, RNE
  unsigned u = __float_as_uint(f);
  u += 0x7fffu + ((u >> 16) & 1u);
  return (unsigned short)(u >> 16);
}
__device__ inline float bf2f(unsigned short s) {
  return __uint_as_float(((unsigned)s) << 16);
}

// ---------------- CSR construction ----------------

__global__ __launch_bounds__(256) void k_count(const int* __restrict__ dst,
                                               int* __restrict__ deg, int E) {
  int e = blockIdx.x * 256 + threadIdx.x;
  if (e < E) atomicAdd(&deg[dst[e]], 1);
}

__global__ __launch_bounds__(256) void k_dis(const int* __restrict__ deg,
                                             float* __restrict__ dis, int N) {
  int i = blockIdx.x * 256 + threadIdx.x;
  if (i < N) dis[i] = rsqrtf((float)(deg[i] + 1));  // +1 self-loop
}

__global__ __launch_bounds__(256) void k_scanA(const int* __restrict__ deg,
                                               int* __restrict__ offtmp,
                                               int* __restrict__ bsum, int N) {
  __shared__ int s[256];
  int i = blockIdx.x * 256 + threadIdx.x;
  int v = (i < N) ? deg[i] : 0;
  s[threadIdx.x] = v;
  __syncthreads();
#pragma unroll
  for (int ofs = 1; ofs < 256; ofs <<= 1) {
    int t = (threadIdx.x >= ofs) ? s[threadIdx.x - ofs] : 0;
    __syncthreads();
    s[threadIdx.x] += t;
    __syncthreads();
  }
  if (i < N) offtmp[i] = s[threadIdx.x] - v;  // exclusive
  if (threadIdx.x == 255) bsum[blockIdx.x] = s[255];
}

// parallel exclusive scan of block sums (nb <= 512)
__global__ __launch_bounds__(512) void k_scanB(int* __restrict__ bsum, int nb) {
  __shared__ int s[512];
  int t = threadIdx.x;
  int v = (t < nb) ? bsum[t] : 0;
  s[t] = v;
  __syncthreads();
#pragma unroll
  for (int ofs = 1; ofs < 512; ofs <<= 1) {
    int u = (t >= ofs) ? s[t - ofs] : 0;
    __syncthreads();
    s[t] += u;
    __syncthreads();
  }
  if (t < nb) bsum[t] = s[t] - v;  // exclusive
}

__global__ __launch_bounds__(256) void k_scanC(const int* __restrict__ offtmp,
                                               const int* __restrict__ bsum,
                                               int* __restrict__ off, int N, int E) {
  int i = blockIdx.x * 256 + threadIdx.x;
  if (i < N) off[i] = offtmp[i] + bsum[i >> 8];
  if (i == 0) off[N] = E;
}

// packed edge record: .x = src, .y = bits(dis[src]*dis[dst])
__global__ __launch_bounds__(256) void k_fill(const int* __restrict__ src,
                                              const int* __restrict__ dst,
                                              const float* __restrict__ dis,
                                              const int* __restrict__ off,
                                              int* __restrict__ cursor,
                                              int2* __restrict__ ew, int E) {
  int e = blockIdx.x * 256 + threadIdx.x;
  if (e >= E) return;
  int d = dst[e], s = src[e];
  int pos = off[d] + atomicAdd(&cursor[d], 1);
  ew[pos] = make_int2(s, __float_as_int(dis[s] * dis[d]));
}

// ---------------- W pre-swizzle: fp32 W -> hi/lo bf16 in MFMA B-frag order ----
// Wf[ct][kt][lane][j]: k = kt*32 + (lane>>4)*8 + j, n = ct*16 + (lane&15)
__global__ __launch_bounds__(256) void k_wsplit(const float* __restrict__ W,
                                                short* __restrict__ hi,
                                                short* __restrict__ lo) {
  int idx = blockIdx.x * 256 + threadIdx.x;  // 0..16383
  int j = idx & 7, lane = (idx >> 3) & 63, kt = (idx >> 9) & 3, ct = idx >> 11;
  int k = kt * 32 + (lane >> 4) * 8 + j;
  int n = ct * 16 + (lane & 15);
  float w = W[k * FD + n];
  unsigned short h = f2bf(w);
  hi[idx] = (short)h;
  lo[idx] = (short)f2bf(w - bf2f(h));
}

// ---------------- GEMM: H(bf16) = A @ W via bf16 MFMA ----------------
// W hi/lo fragments staged in LDS (64 KB) per block. 4 waves/block, 32 rows/wave
// (2 M-tiles sharing each B fragment); block covers 128 rows.
// ABF16=false: A fp32, split hi/lo in-register (3 mfma/tile/kt).
// ABF16=true:  A bf16 (2 mfma/tile/kt: Ahi*Whi + Ahi*Wlo).
template <bool ABF16>
__global__ __launch_bounds__(256) void k_gemm(const void* __restrict__ Av,
                                              const short* __restrict__ Wf_hi,
                                              const short* __restrict__ Wf_lo,
                                              unsigned short* __restrict__ H, int N) {
  __shared__ short whi[FD * FD], wlo[FD * FD];  // 32 KB + 32 KB
  int tid = threadIdx.x;
#pragma unroll
  for (int it = 0; it < 8; ++it) {
    int idx = (it * 256 + tid) * 8;  // 8 shorts = 16 B per thread per iter
    *(short8*)&whi[idx] = *(const short8*)&Wf_hi[idx];
    *(short8*)&wlo[idx] = *(const short8*)&Wf_lo[idx];
  }
  __syncthreads();

  int wid = tid >> 6, lane = tid & 63;
  int quad = lane >> 4, m = lane & 15;
  int rbase = blockIdx.x * 128 + wid * 32;

  short8 ahi[2][4], alo[2][4];
#pragma unroll
  for (int t = 0; t < 2; ++t) {
    int arow = rbase + t * 16 + m;
    if (arow >= N) arow = N - 1;  // clamp; OOB rows never stored
    if (ABF16) {
      const unsigned short* ap = (const unsigned short*)Av + (size_t)arow * FD;
#pragma unroll
      for (int kt = 0; kt < 4; ++kt)
        ahi[t][kt] = *(const short8*)(ap + kt * 32 + quad * 8);
    } else {
      const float* ap = (const float*)Av + (size_t)arow * FD;
#pragma unroll
      for (int kt = 0; kt < 4; ++kt) {
        const float* p = ap + kt * 32 + quad * 8;
        float4 a0 = *(const float4*)p;
        float4 a1 = *(const float4*)(p + 4);
        float av[8] = {a0.x, a0.y, a0.z, a0.w, a1.x, a1.y, a1.z, a1.w};
#pragma unroll
        for (int j = 0; j < 8; ++j) {
          unsigned short hb = f2bf(av[j]);
          ahi[t][kt][j] = (short)hb;
          alo[t][kt][j] = (short)f2bf(av[j] - bf2f(hb));
        }
      }
    }
  }

#pragma unroll
  for (int ct = 0; ct < 8; ++ct) {
    floatx4 acc0 = {0.f, 0.f, 0.f, 0.f}, acc1 = {0.f, 0.f, 0.f, 0.f};
#pragma unroll
    for (int kt = 0; kt < 4; ++kt) {
      int fo = (((ct << 2) + kt) * 64 + lane) * 8;
      short8 bhi = *(const short8*)&whi[fo];
      short8 blo = *(const short8*)&wlo[fo];
      acc0 = __builtin_amdgcn_mfma_f32_16x16x32_bf16(ahi[0][kt], bhi, acc0, 0, 0, 0);
      acc1 = __builtin_amdgcn_mfma_f32_16x16x32_bf16(ahi[1][kt], bhi, acc1, 0, 0, 0);
      if (!ABF16) {
        acc0 = __builtin_amdgcn_mfma_f32_16x16x32_bf16(alo[0][kt], bhi, acc0, 0, 0, 0);
        acc1 = __builtin_amdgcn_mfma_f32_16x16x32_bf16(alo[1][kt], bhi, acc1, 0, 0, 0);
      }
      acc0 = __builtin_amdgcn_mfma_f32_16x16x32_bf16(ahi[0][kt], blo, acc0, 0, 0, 0);
      acc1 = __builtin_amdgcn_mfma_f32_16x16x32_bf16(ahi[1][kt], blo, acc1, 0, 0, 0);
    }
    // C/D: row = quad*4 + reg, col = lane&15
#pragma unroll
    for (int r = 0; r < 4; ++r) {
      int row0 = rbase + quad * 4 + r;
      int row1 = rbase + 16 + quad * 4 + r;
      if (row0 < N) H[(size_t)row0 * FD + ct * 16 + m] = f2bf(acc0[r]);
      if (row1 < N) H[(size_t)row1 * FD + ct * 16 + m] = f2bf(acc1[r]);
    }
  }
}

// ---------------- Aggregation: out = relu(A_norm @ h + b), h is bf16 --------
// One wave per node; lane holds 1 dword = 2 bf16 features. Edge records are
// wave-uniform -> scalar loads. OUTBF16: pack output to bf16 (intermediate x).
template <bool OUTBF16>
__global__ __launch_bounds__(256) void k_agg(const unsigned int* __restrict__ h,
                                             const int* __restrict__ off,
                                             const int2* __restrict__ ew,
                                             const float* __restrict__ dis,
                                             const float* __restrict__ bias,
                                             void* __restrict__ out, int N) {
  int wid = __builtin_amdgcn_readfirstlane(threadIdx.x >> 6);  // wave-uniform
  int lane = threadIdx.x & 63;
  int i = blockIdx.x * 4 + wid;
  if (i >= N) return;
  float di = dis[i];
  float wself = di * di;
  unsigned v = h[(size_t)i * 64 + lane];
  float a0 = wself * __uint_as_float(v << 16);
  float a1 = wself * __uint_as_float(v & 0xffff0000u);
  float b0 = 0.f, b1 = 0.f, c0 = 0.f, c1 = 0.f, d0 = 0.f, d1 = 0.f;
  int p = off[i], p1 = off[i + 1];
  for (; p + 3 < p1; p += 4) {
    int2 e0 = ew[p], e1 = ew[p + 1], e2 = ew[p + 2], e3 = ew[p + 3];
    unsigned v0 = h[(size_t)e0.x * 64 + lane];
    unsigned v1 = h[(size_t)e1.x * 64 + lane];
    unsigned v2 = h[(size_t)e2.x * 64 + lane];
    unsigned v3 = h[(size_t)e3.x * 64 + lane];
    float w0 = __int_as_float(e0.y), w1 = __int_as_float(e1.y);
    float w2 = __int_as_float(e2.y), w3 = __int_as_float(e3.y);
    a0 = fmaf(w0, __uint_as_float(v0 << 16), a0);
    a1 = fmaf(w0, __uint_as_float(v0 & 0xffff0000u), a1);
    b0 = fmaf(w1, __uint_as_float(v1 << 16), b0);
    b1 = fmaf(w1, __uint_as_float(v1 & 0xffff0000u), b1);
    c0 = fmaf(w2, __uint_as_float(v2 << 16), c0);
    c1 = fmaf(w2, __uint_as_float(v2 & 0xffff0000u), c1);
    d0 = fmaf(w3, __uint_as_float(v3 << 16), d0);
    d1 = fmaf(w3, __uint_as_float(v3 & 0xffff0000u), d1);
  }
  for (; p < p1; ++p) {
    int2 e0 = ew[p];
    unsigned v0 = h[(size_t)e0.x * 64 + lane];
    float w0 = __int_as_float(e0.y);
    a0 = fmaf(w0, __uint_as_float(v0 << 16), a0);
    a1 = fmaf(w0, __uint_as_float(v0 & 0xffff0000u), a1);
  }
  float2 bb = ((const float2*)bias)[lane];
  float o0 = fmaxf(a0 + b0 + c0 + d0 + bb.x, 0.f);
  float o1 = fmaxf(a1 + b1 + c1 + d1 + bb.y, 0.f);
  if (OUTBF16) {
    unsigned pk = ((unsigned)f2bf(o1) << 16) | (unsigned)f2bf(o0);
    ((unsigned*)out)[(size_t)i * 64 + lane] = pk;
  } else {
    ((float2*)out)[(size_t)i * 64 + lane] = make_float2(o0, o1);
  }
}

// ---------------- launch ----------------

extern "C" void kernel_launch(void* const* d_in, const int* in_sizes, int n_in,
                              void* d_out, int out_size, void* d_ws, size_t ws_size,
                              hipStream_t stream) {
  const float* x = (const float*)d_in[0];
  const int* ei = (const int*)d_in[1];
  const float* Wg = (const float*)d_in[2];
  const float* b = (const float*)d_in[3];
  int N = in_sizes[0] / FD;
  int E = in_sizes[1] / 2;
  const int* src = ei;      // edge_index[0]
  const int* dst = ei + E;  // edge_index[1]

  char* p = (char*)d_ws;
  auto alloc = [&](size_t bytes) {
    void* r = (void*)p;
    p += (bytes + 255) & ~(size_t)255;
    return r;
  };
  int* deg = (int*)alloc((size_t)N * 4);
  int* cursor = (int*)alloc((size_t)N * 4);
  float* dis = (float*)alloc((size_t)N * 4);
  int* offtmp = (int*)alloc((size_t)N * 4);
  int nb = (N + 255) / 256;
  int* bsum = (int*)alloc((size_t)nb * 4);
  int* off = (int*)alloc((size_t)(N + 1) * 4);
  int2* ew = (int2*)alloc((size_t)E * 8);
  unsigned short* h = (unsigned short*)alloc((size_t)N * FD * 2);   // bf16 H
  unsigned short* xb = (unsigned short*)alloc((size_t)N * FD * 2);  // bf16 x (layers 1,2)
  short* wf_hi = (short*)alloc((size_t)FD * FD * 2);
  short* wf_lo = (short*)alloc((size_t)FD * FD * 2);

  hipMemsetAsync(deg, 0, (size_t)N * 4, stream);
  hipMemsetAsync(cursor, 0, (size_t)N * 4, stream);

  int gE = (E + 255) / 256, gN = (N + 255) / 256;
  k_count<<<gE, 256, 0, stream>>>(dst, deg, E);
  k_dis<<<gN, 256, 0, stream>>>(deg, dis, N);
  k_scanA<<<nb, 256, 0, stream>>>(deg, offtmp, bsum, N);
  k_scanB<<<1, 512, 0, stream>>>(bsum, nb);
  k_scanC<<<gN, 256, 0, stream>>>(offtmp, bsum, off, N, E);
  k_fill<<<gE, 256, 0, stream>>>(src, dst, dis, off, cursor, ew, E);
  k_wsplit<<<FD * FD / 256, 256, 0, stream>>>(Wg, wf_hi, wf_lo);

  int gG = (N + 127) / 128;
  int gA = (N + 3) / 4;
  // layer 0: fp32 x -> h; agg -> bf16 xb
  k_gemm<false><<<gG, 256, 0, stream>>>(x, wf_hi, wf_lo, h, N);
  k_agg<true><<<gA, 256, 0, stream>>>((const unsigned*)h, off, ew, dis, b, xb, N);
  // layer 1: bf16 xb -> h; agg -> bf16 xb
  k_gemm<true><<<gG, 256, 0, stream>>>(xb, wf_hi, wf_lo, h, N);
  k_agg<true><<<gA, 256, 0, stream>>>((const unsigned*)h, off, ew, dis, b, xb, N);
  // layer 2: bf16 xb -> h; agg -> fp32 d_out
  k_gemm<true><<<gG, 256, 0, stream>>>(xb, wf_hi, wf_lo, h, N);
  k_agg<false><<<gA, 256, 0, stream>>>((const unsigned*)h, off, ew, dis, b, d_out, N);
}